// Round 5
// baseline (516.193 us; speedup 1.0000x reference)
//
#include <hip/hip_runtime.h>

#define EPS 1e-5f
#define NC 256
#define NT 251
#define NF 7
#define NSP 1757   // NF*NT
#define NB 32

// workspace layout (float offsets) — total 2592 floats (~10.4 KB)
#define OFF_QEC 0
#define OFF_KEC 256
#define OFF_QEF 512
#define OFF_KEF 768
#define OFF_QET 1024
#define OFF_KET 1280
#define OFF_VSC 1536
#define OFF_VOF 1792
#define OFF_CONST 2048   // [0..5]=q/k consts c,f,t  [6]=s_c [7]=s_f [8]=s_t
#define OFF_DC 2064      // 256
#define OFF_DF 2320      // 256 (251 used)
#define OFF_DT 2576      // 16 (7 used)
#define WS_END 2592

// ---------------------------------------------------------------- prep
__global__ __launch_bounds__(256) void prep_kernel(
    const float* qc_w, const float* qc_bn, const float* kc_w, const float* kc_bn, const float* lc_bn,
    const float* qf_w, const float* qf_bn, const float* kf_w, const float* kf_bn, const float* lf_bn,
    const float* qt_w, const float* qt_bn, const float* kt_w, const float* kt_bn, const float* lt_bn,
    const float* v_b, const float* v_bn, float* ws)
{
    int tid = threadIdx.x;
    int blk = blockIdx.x;
    __shared__ float red[256];
    if (blk < 6) {
        const float* w; const float* bn; float* out; int O; float* cdst;
        switch (blk) {
            case 0: w=qc_w; bn=qc_bn; out=ws+OFF_QEC; O=NT; cdst=ws+OFF_CONST+0; break;
            case 1: w=kc_w; bn=kc_bn; out=ws+OFF_KEC; O=NT; cdst=ws+OFF_CONST+1; break;
            case 2: w=qf_w; bn=qf_bn; out=ws+OFF_QEF; O=NC; cdst=ws+OFF_CONST+2; break;
            case 3: w=kf_w; bn=kf_bn; out=ws+OFF_KEF; O=NC; cdst=ws+OFF_CONST+3; break;
            case 4: w=qt_w; bn=qt_bn; out=ws+OFF_QET; O=NC; cdst=ws+OFF_CONST+4; break;
            default: w=kt_w; bn=kt_bn; out=ws+OFF_KET; O=NC; cdst=ws+OFF_CONST+5; break;
        }
        float invO = 1.0f / (float)O;
        if (tid < O) {
            float acc = 0.f;
            for (int o = 0; o < O; ++o) {
                float g = bn[o], vv = bn[3*O+o];
                float sc = g * rsqrtf(vv + EPS);
                acc = fmaf(sc, w[o*O + tid], acc);
            }
            out[tid] = acc * invO;
        }
        float bs = 0.f;
        for (int o = tid; o < O; o += 256) {
            float sc = bn[o] * rsqrtf(bn[3*O+o] + EPS);
            bs += bn[O+o] - bn[2*O+o]*sc;
        }
        red[tid] = bs; __syncthreads();
        for (int s = 128; s > 0; s >>= 1) { if (tid < s) red[tid] += red[tid+s]; __syncthreads(); }
        if (tid == 0) *cdst = red[0] * invO;
    } else {
        if (tid < NC) {
            float s = v_bn[tid] * rsqrtf(v_bn[3*NC+tid] + EPS);
            ws[OFF_VSC+tid] = s;
            ws[OFF_VOF+tid] = v_bn[NC+tid] - v_bn[2*NC+tid]*s + v_b[tid]*s;
        }
        if (tid == 0) {
            ws[OFF_CONST+6] = lc_bn[0] * rsqrtf(lc_bn[3] + EPS);
            ws[OFF_CONST+7] = lf_bn[0] * rsqrtf(lf_bn[3] + EPS);
            ws[OFF_CONST+8] = lt_bn[0] * rsqrtf(lt_bn[3] + EPS);
        }
        // zero the d accumulators (ws is poisoned 0xAA every call)
        for (int i = tid; i < WS_END - OFF_DC; i += 256) ws[OFF_DC + i] = 0.f;
    }
}

// --------------------------------- qv/kv + diag softmax for c and f branches
// block per n=(b,f). Stages x[b, ch_chunk(64), f, :] transposed into LDS (fp32).
__global__ __launch_bounds__(256) void qkv_cf_kernel(const float* __restrict__ x, float* __restrict__ ws)
{
    __shared__ float xs[NT*65];   // 251 x (64+1 pad) x 4B = 65260 B
    int tid = threadIdx.x;
    int n = blockIdx.x;
    int b = n / NF, f = n % NF;
    const float* xb = x + (size_t)b*NC*NSP + (size_t)f*NT;
    int wv = tid >> 6, ln = tid & 63;
    const float* cst = ws + OFF_CONST;
    float qc = 0.f, kc = 0.f, qf = 0.f, kf = 0.f;

    for (int chunk = 0; chunk < 4; ++chunk) {
        int ch0 = chunk * 64;
        if (chunk) __syncthreads();
        // stage 64 channels; wave wv handles ch = i*4+wv; lanes stream t (coalesced)
        for (int i = 0; i < 16; ++i) {
            int ch = (i << 2) + wv;
            const float* xr = xb + (size_t)(ch0 + ch)*NSP;
            #pragma unroll
            for (int j = 0; j < 4; ++j) {
                int t = ln + j*64;
                if (t < NT) xs[t*65 + ch] = xr[t];
            }
        }
        __syncthreads();
        // c-branch: thread == global channel; active only during its chunk
        if ((tid >> 6) == chunk) {
            int chl = tid & 63;
            const float* qeC = ws + OFF_QEC;
            const float* keC = ws + OFF_KEC;
            for (int t = 0; t < NT; ++t) {
                float xv = xs[t*65 + chl];
                qc = fmaf(qeC[t], xv, qc);
                kc = fmaf(keC[t], xv, kc);
            }
        }
        // f-branch: thread == t, accumulate this chunk's 64 channels
        if (tid < NT) {
            const float* qeF = ws + OFF_QEF;
            const float* keF = ws + OFF_KEF;
            for (int ch = 0; ch < 64; ++ch) {
                float xv = xs[tid*65 + ch];
                int cg = ch0 + ch;
                qf = fmaf(qeF[cg], xv, qf);
                kf = fmaf(keF[cg], xv, kf);
            }
        }
    }
    qc += cst[0]; kc += cst[1];
    qf += cst[2]; kf += cst[3];

    __syncthreads();                 // all xs reads done; reuse LDS
    float* kvc = xs;                 // 256 floats
    float* kvf = xs + 256;           // 251 floats
    kvc[tid] = kc;
    if (tid < NT) kvf[tid] = kf;
    __syncthreads();

    {   // c diag softmax, channel = tid
        float s = cst[6];
        float qi = s * qc;
        float m = -1e30f;
        for (int j = 0; j < NC; ++j) m = fmaxf(m, qi*kvc[j]);
        float den = 0.f;
        for (int j = 0; j < NC; ++j) den += __expf(qi*kvc[j] - m);
        atomicAdd(&ws[OFF_DC + tid], __expf(qi*kc - m)/den);
    }
    if (tid < NT) {   // f diag softmax, t = tid
        float s = cst[7];
        float qi = s * qf;
        float m = -1e30f;
        for (int j = 0; j < NT; ++j) m = fmaxf(m, qi*kvf[j]);
        float den = 0.f;
        for (int j = 0; j < NT; ++j) den += __expf(qi*kvf[j] - m);
        atomicAdd(&ws[OFF_DF + tid], __expf(qi*kf - m)/den);
    }
}

// --------------------------- t-branch: block per (b, t-slice of 32)
__global__ __launch_bounds__(256) void t_kernel(const float* __restrict__ x, float* __restrict__ ws)
{
    __shared__ float qs[32*NF], ks[32*NF], dt_acc[NF];
    int tid = threadIdx.x;
    int b  = blockIdx.x >> 3;
    int t0 = (blockIdx.x & 7) * 32;
    int tl = tid & 31, fr = tid >> 5;     // fr 0..7 (7 inactive)
    int t = t0 + tl;
    bool act = (fr < NF) && (t < NT);
    if (tid < NF) dt_acc[tid] = 0.f;

    float aq = 0.f, ak = 0.f;
    const float* qeT = ws + OFF_QET;
    const float* keT = ws + OFF_KET;
    if (act) {
        const float* xr = x + (size_t)b*NC*NSP + fr*NT + t;
        for (int ch = 0; ch < NC; ++ch) {
            float xv = xr[(size_t)ch*NSP];
            aq = fmaf(qeT[ch], xv, aq);
            ak = fmaf(keT[ch], xv, ak);
        }
    }
    __syncthreads();
    if (act) {
        qs[tl*NF + fr] = aq + ws[OFF_CONST+4];
        ks[tl*NF + fr] = ak + ws[OFF_CONST+5];
    }
    __syncthreads();
    if (act) {
        float s = ws[OFF_CONST+8];
        float qi = s * qs[tl*NF + fr];
        float m = -1e30f;
        #pragma unroll
        for (int j = 0; j < NF; ++j) m = fmaxf(m, qi*ks[tl*NF + j]);
        float den = 0.f;
        #pragma unroll
        for (int j = 0; j < NF; ++j) den += __expf(qi*ks[tl*NF + j] - m);
        atomicAdd(&dt_acc[fr], __expf(qi*ks[tl*NF + fr] - m)/den);
    }
    __syncthreads();
    if (tid < NF) atomicAdd(&ws[OFF_DT + tid], dt_acc[tid]);
}

// ---------------------------------------------- main GEMM (v branch) + epilogue
#define BO 64
#define BN 64
#define BK 32
__global__ __launch_bounds__(256) void main_kernel(
    const float* __restrict__ x, const float* __restrict__ vw,
    const float* __restrict__ ws, float* __restrict__ out)
{
    __shared__ float Wt[BK][BO+1];
    __shared__ float Xt[BK][BN+1];
    int tid = threadIdx.x;
    int n0 = blockIdx.x * BN;
    int o0 = blockIdx.y * BO;
    int b  = blockIdx.z;
    const size_t xbase = (size_t)b * NC * NSP;
    float acc[4][4] = {};
    int tx = tid & 15, ty = tid >> 4;

    for (int k0 = 0; k0 < NC; k0 += BK) {
        {   // stage W tile transposed: Wt[kk][oo]
            int oo = tid >> 2, kg = tid & 3;
            const float* wr = vw + (size_t)(o0+oo)*NC + k0 + kg*8;
            #pragma unroll
            for (int j = 0; j < 8; ++j) Wt[kg*8+j][oo] = wr[j];
        }
        {   // stage X tile: Xt[kk][nn]
            int kk = tid >> 3, ng = tid & 7;
            const float* xr = x + xbase + (size_t)(k0+kk)*NSP + n0 + ng*8;
            #pragma unroll
            for (int j = 0; j < 8; ++j) {
                int nn = n0 + ng*8 + j;
                Xt[kk][ng*8+j] = (nn < NSP) ? xr[j] : 0.f;
            }
        }
        __syncthreads();
        #pragma unroll
        for (int kk = 0; kk < BK; ++kk) {
            float a[4], bb[4];
            #pragma unroll
            for (int i = 0; i < 4; ++i) a[i] = Wt[kk][ty*4+i];
            #pragma unroll
            for (int j = 0; j < 4; ++j) bb[j] = Xt[kk][tx*4+j];
            #pragma unroll
            for (int i = 0; i < 4; ++i)
                #pragma unroll
                for (int j = 0; j < 4; ++j)
                    acc[i][j] = fmaf(a[i], bb[j], acc[i][j]);
        }
        __syncthreads();
    }

    const float* dc = ws + OFF_DC;
    const float* df = ws + OFF_DF;
    const float* dt = ws + OFF_DT;
    #pragma unroll
    for (int i = 0; i < 4; ++i) {
        int o = o0 + ty*4 + i;
        float vs = ws[OFF_VSC+o], vo = ws[OFF_VOF+o], dcv = dc[o];
        #pragma unroll
        for (int j = 0; j < 4; ++j) {
            int nn = n0 + tx*4 + j;
            if (nn < NSP) {
                int f = nn / NT, t = nn - f*NT;
                float fac = dcv + dt[f] + df[t];
                size_t gi = xbase + (size_t)o*NSP + nn;
                out[gi] = (acc[i][j]*vs + vo)*fac + x[gi];
            }
        }
    }
}

extern "C" void kernel_launch(void* const* d_in, const int* in_sizes, int n_in,
                              void* d_out, int out_size, void* d_ws, size_t ws_size,
                              hipStream_t stream)
{
    const float* x    = (const float*)d_in[0];
    const float* qc_w = (const float*)d_in[1];  const float* qc_bn = (const float*)d_in[2];
    const float* kc_w = (const float*)d_in[3];  const float* kc_bn = (const float*)d_in[4];
    const float* lc_bn= (const float*)d_in[5];
    const float* qf_w = (const float*)d_in[6];  const float* qf_bn = (const float*)d_in[7];
    const float* kf_w = (const float*)d_in[8];  const float* kf_bn = (const float*)d_in[9];
    const float* lf_bn= (const float*)d_in[10];
    const float* qt_w = (const float*)d_in[11]; const float* qt_bn = (const float*)d_in[12];
    const float* kt_w = (const float*)d_in[13]; const float* kt_bn = (const float*)d_in[14];
    const float* lt_bn= (const float*)d_in[15];
    const float* v_w  = (const float*)d_in[16]; const float* v_b   = (const float*)d_in[17];
    const float* v_bn = (const float*)d_in[18];
    float* ws = (float*)d_ws;
    float* out = (float*)d_out;

    prep_kernel<<<7, 256, 0, stream>>>(qc_w,qc_bn,kc_w,kc_bn,lc_bn,
                                       qf_w,qf_bn,kf_w,kf_bn,lf_bn,
                                       qt_w,qt_bn,kt_w,kt_bn,lt_bn,
                                       v_b,v_bn,ws);
    qkv_cf_kernel<<<NB*NF, 256, 0, stream>>>(x, ws);
    t_kernel<<<NB*8, 256, 0, stream>>>(x, ws);
    main_kernel<<<dim3((NSP+BN-1)/BN, NC/BO, NB), 256, 0, stream>>>(x, v_w, ws, out);
}

// Round 6
// 405.960 us; speedup vs baseline: 1.2715x; 1.2715x over previous
//
#include <hip/hip_runtime.h>

typedef unsigned short u16;
typedef __attribute__((ext_vector_type(8))) short short8;
typedef __attribute__((ext_vector_type(4))) float float4v;

#define EPS 1e-5f
#define NC 256
#define NT 251
#define NF 7
#define NSP 1757   // NF*NT
#define NB 32

// workspace layout (float offsets) — total 2592 floats (~10.4 KB)
#define OFF_QEC 0
#define OFF_KEC 256
#define OFF_QEF 512
#define OFF_KEF 768
#define OFF_QET 1024
#define OFF_KET 1280
#define OFF_VSC 1536
#define OFF_VOF 1792
#define OFF_CONST 2048   // [0..5]=q/k consts c,f,t  [6]=s_c [7]=s_f [8]=s_t
#define OFF_DC 2064      // 256
#define OFF_DF 2320      // 256 (251 used)
#define OFF_DT 2576      // 16 (7 used)
#define WS_END 2592

__device__ __forceinline__ u16 f2b(float f) {   // fp32 -> bf16 RNE
    unsigned int u = __float_as_uint(f);
    return (u16)((u + 0x7FFFu + ((u >> 16) & 1u)) >> 16);
}

// ---------------------------------------------------------------- prep
__global__ __launch_bounds__(256) void prep_kernel(
    const float* qc_w, const float* qc_bn, const float* kc_w, const float* kc_bn, const float* lc_bn,
    const float* qf_w, const float* qf_bn, const float* kf_w, const float* kf_bn, const float* lf_bn,
    const float* qt_w, const float* qt_bn, const float* kt_w, const float* kt_bn, const float* lt_bn,
    const float* v_b, const float* v_bn, float* ws)
{
    int tid = threadIdx.x;
    int blk = blockIdx.x;
    __shared__ float red[256];
    if (blk < 6) {
        const float* w; const float* bn; float* out; int O; float* cdst;
        switch (blk) {
            case 0: w=qc_w; bn=qc_bn; out=ws+OFF_QEC; O=NT; cdst=ws+OFF_CONST+0; break;
            case 1: w=kc_w; bn=kc_bn; out=ws+OFF_KEC; O=NT; cdst=ws+OFF_CONST+1; break;
            case 2: w=qf_w; bn=qf_bn; out=ws+OFF_QEF; O=NC; cdst=ws+OFF_CONST+2; break;
            case 3: w=kf_w; bn=kf_bn; out=ws+OFF_KEF; O=NC; cdst=ws+OFF_CONST+3; break;
            case 4: w=qt_w; bn=qt_bn; out=ws+OFF_QET; O=NC; cdst=ws+OFF_CONST+4; break;
            default: w=kt_w; bn=kt_bn; out=ws+OFF_KET; O=NC; cdst=ws+OFF_CONST+5; break;
        }
        float invO = 1.0f / (float)O;
        if (tid < O) {
            float acc = 0.f;
            for (int o = 0; o < O; ++o) {
                float g = bn[o], vv = bn[3*O+o];
                float sc = g * rsqrtf(vv + EPS);
                acc = fmaf(sc, w[o*O + tid], acc);
            }
            out[tid] = acc * invO;
        }
        float bs = 0.f;
        for (int o = tid; o < O; o += 256) {
            float sc = bn[o] * rsqrtf(bn[3*O+o] + EPS);
            bs += bn[O+o] - bn[2*O+o]*sc;
        }
        red[tid] = bs; __syncthreads();
        for (int s = 128; s > 0; s >>= 1) { if (tid < s) red[tid] += red[tid+s]; __syncthreads(); }
        if (tid == 0) *cdst = red[0] * invO;
    } else {
        if (tid < NC) {
            float s = v_bn[tid] * rsqrtf(v_bn[3*NC+tid] + EPS);
            ws[OFF_VSC+tid] = s;
            ws[OFF_VOF+tid] = v_bn[NC+tid] - v_bn[2*NC+tid]*s + v_b[tid]*s;
        }
        if (tid == 0) {
            ws[OFF_CONST+6] = lc_bn[0] * rsqrtf(lc_bn[3] + EPS);
            ws[OFF_CONST+7] = lf_bn[0] * rsqrtf(lf_bn[3] + EPS);
            ws[OFF_CONST+8] = lt_bn[0] * rsqrtf(lt_bn[3] + EPS);
        }
        // zero the d accumulators (ws is poisoned 0xAA every call)
        for (int i = tid; i < WS_END - OFF_DC; i += 256) ws[OFF_DC + i] = 0.f;
    }
}

// --------------------------------- qv/kv + diag softmax for c and f branches
__global__ __launch_bounds__(256) void qkv_cf_kernel(const float* __restrict__ x, float* __restrict__ ws)
{
    __shared__ float xs[NT*65];   // 251 x (64+1 pad) x 4B = 65260 B
    int tid = threadIdx.x;
    int n = blockIdx.x;
    int b = n / NF, f = n % NF;
    const float* xb = x + (size_t)b*NC*NSP + (size_t)f*NT;
    int wv = tid >> 6, ln = tid & 63;
    const float* cst = ws + OFF_CONST;
    float qc = 0.f, kc = 0.f, qf = 0.f, kf = 0.f;

    for (int chunk = 0; chunk < 4; ++chunk) {
        int ch0 = chunk * 64;
        if (chunk) __syncthreads();
        for (int i = 0; i < 16; ++i) {
            int ch = (i << 2) + wv;
            const float* xr = xb + (size_t)(ch0 + ch)*NSP;
            #pragma unroll
            for (int j = 0; j < 4; ++j) {
                int t = ln + j*64;
                if (t < NT) xs[t*65 + ch] = xr[t];
            }
        }
        __syncthreads();
        if ((tid >> 6) == chunk) {
            int chl = tid & 63;
            const float* qeC = ws + OFF_QEC;
            const float* keC = ws + OFF_KEC;
            for (int t = 0; t < NT; ++t) {
                float xv = xs[t*65 + chl];
                qc = fmaf(qeC[t], xv, qc);
                kc = fmaf(keC[t], xv, kc);
            }
        }
        if (tid < NT) {
            const float* qeF = ws + OFF_QEF;
            const float* keF = ws + OFF_KEF;
            for (int ch = 0; ch < 64; ++ch) {
                float xv = xs[tid*65 + ch];
                int cg = ch0 + ch;
                qf = fmaf(qeF[cg], xv, qf);
                kf = fmaf(keF[cg], xv, kf);
            }
        }
    }
    qc += cst[0]; kc += cst[1];
    qf += cst[2]; kf += cst[3];

    __syncthreads();
    float* kvc = xs;
    float* kvf = xs + 256;
    kvc[tid] = kc;
    if (tid < NT) kvf[tid] = kf;
    __syncthreads();

    {
        float s = cst[6];
        float qi = s * qc;
        float m = -1e30f;
        for (int j = 0; j < NC; ++j) m = fmaxf(m, qi*kvc[j]);
        float den = 0.f;
        for (int j = 0; j < NC; ++j) den += __expf(qi*kvc[j] - m);
        atomicAdd(&ws[OFF_DC + tid], __expf(qi*kc - m)/den);
    }
    if (tid < NT) {
        float s = cst[7];
        float qi = s * qf;
        float m = -1e30f;
        for (int j = 0; j < NT; ++j) m = fmaxf(m, qi*kvf[j]);
        float den = 0.f;
        for (int j = 0; j < NT; ++j) den += __expf(qi*kvf[j] - m);
        atomicAdd(&ws[OFF_DF + tid], __expf(qi*kf - m)/den);
    }
}

// --------------------------- t-branch: block per (b, t-slice of 32)
__global__ __launch_bounds__(256) void t_kernel(const float* __restrict__ x, float* __restrict__ ws)
{
    __shared__ float qs[32*NF], ks[32*NF], dt_acc[NF];
    int tid = threadIdx.x;
    int b  = blockIdx.x >> 3;
    int t0 = (blockIdx.x & 7) * 32;
    int tl = tid & 31, fr = tid >> 5;
    int t = t0 + tl;
    bool act = (fr < NF) && (t < NT);
    if (tid < NF) dt_acc[tid] = 0.f;

    float aq = 0.f, ak = 0.f;
    const float* qeT = ws + OFF_QET;
    const float* keT = ws + OFF_KET;
    if (act) {
        const float* xr = x + (size_t)b*NC*NSP + fr*NT + t;
        #pragma unroll 8
        for (int ch = 0; ch < NC; ++ch) {
            float xv = xr[(size_t)ch*NSP];
            aq = fmaf(qeT[ch], xv, aq);
            ak = fmaf(keT[ch], xv, ak);
        }
    }
    __syncthreads();
    if (act) {
        qs[tl*NF + fr] = aq + ws[OFF_CONST+4];
        ks[tl*NF + fr] = ak + ws[OFF_CONST+5];
    }
    __syncthreads();
    if (act) {
        float s = ws[OFF_CONST+8];
        float qi = s * qs[tl*NF + fr];
        float m = -1e30f;
        #pragma unroll
        for (int j = 0; j < NF; ++j) m = fmaxf(m, qi*ks[tl*NF + j]);
        float den = 0.f;
        #pragma unroll
        for (int j = 0; j < NF; ++j) den += __expf(qi*ks[tl*NF + j] - m);
        atomicAdd(&dt_acc[fr], __expf(qi*ks[tl*NF + fr] - m)/den);
    }
    __syncthreads();
    if (tid < NF) atomicAdd(&ws[OFF_DT + tid], dt_acc[tid]);
}

// --------------------- main GEMM (v branch) via bf16 MFMA + fused epilogue
// Block tile 128(o) x 128(n), 4 waves in 2x2, wave tile 64x64 = 4x4 frags of
// 16x16, K-step 32 (one mfma_f32_16x16x32_bf16 per frag pair).
// Ws: frag-major [fragO(8)][lane(64)][8] bf16 -> ds_read_b128 conflict-free.
// Xs: natural [k(32)][n(128)+2pad] bf16 -> b32 staging writes conflict-free;
//     B-frags gathered as 8 x ds_read_u16 (bank-clean at pad 130).
#define XP 130
__global__ __launch_bounds__(256) void main_kernel(
    const float* __restrict__ x, const float* __restrict__ vw,
    const float* __restrict__ ws, float* __restrict__ out)
{
    __shared__ u16 Ws[8*512];       // 8 KB
    __shared__ u16 Xs[32*XP];       // 8.3 KB
    __shared__ float vsL[128], voL[128], dcL[128], dtfL[128];

    int tid = threadIdx.x;
    int n0 = blockIdx.x * 128;
    int o0 = blockIdx.y * 128;
    int b  = blockIdx.z;
    const size_t xbase = (size_t)b * NC * NSP;

    // per-block epilogue tables
    if (tid < 128) {
        int o = o0 + tid;
        vsL[tid] = ws[OFF_VSC+o];
        voL[tid] = ws[OFF_VOF+o];
        dcL[tid] = ws[OFF_DC+o];
        int nn = n0 + tid; if (nn > NSP-1) nn = NSP-1;
        int f = nn / NT, t = nn - f*NT;
        dtfL[tid] = ws[OFF_DT+f] + ws[OFF_DF+t];
    }

    int wv = tid >> 6, ln = tid & 63;
    int quad = ln >> 4, l16 = ln & 15;
    int wr = wv >> 1, wc = wv & 1;          // wave at (o-half, n-half)

    float4v acc[4][4] = {};

    // staging roles
    int oo = tid >> 1, half = tid & 1;       // W: 16 k per thread, row oo
    int kk = tid >> 3, ng = tid & 7;         // X: 16 n per thread, row kk

    for (int k0 = 0; k0 < NC; k0 += 32) {
        // ---- stage W tile (128 o x 32 k) to frag-major layout
        {
            const float* wr4 = vw + (size_t)(o0+oo)*NC + k0 + half*16;
            union { u16 us[16]; short8 v[2]; } wb;
            #pragma unroll
            for (int c = 0; c < 16; ++c) wb.us[c] = f2b(wr4[c]);
            int frg = oo >> 4, o16 = oo & 15;
            #pragma unroll
            for (int qq = 0; qq < 2; ++qq) {
                int qd = 2*half + qq;   // quad this 8-chunk belongs to
                *(short8*)&Ws[frg*512 + qd*128 + o16*8] = wb.v[qq];
            }
        }
        // ---- stage X tile (32 k x 128 n), natural layout, packed b32 writes
        {
            int nbase = n0 + ng*16;
            const float* xr = x + xbase + (size_t)(k0+kk)*NSP + nbase;
            u16 xb16[16];
            if (nbase + 15 < NSP) {
                #pragma unroll
                for (int c = 0; c < 16; ++c) xb16[c] = f2b(xr[c]);
            } else {
                #pragma unroll
                for (int c = 0; c < 16; ++c)
                    xb16[c] = (nbase + c < NSP) ? f2b(xr[c]) : (u16)0;
            }
            #pragma unroll
            for (int m = 0; m < 8; ++m) {
                unsigned int pk = (unsigned int)xb16[2*m] | ((unsigned int)xb16[2*m+1] << 16);
                *(unsigned int*)&Xs[kk*XP + ng*16 + 2*m] = pk;
            }
        }
        __syncthreads();

        // ---- fragments + MFMA
        short8 afr[4], bfr[4];
        #pragma unroll
        for (int fr = 0; fr < 4; ++fr)
            afr[fr] = *(short8*)&Ws[(wr*4+fr)*512 + ln*8];
        #pragma unroll
        for (int fc = 0; fc < 4; ++fc) {
            int bb = wc*64 + fc*16 + l16;
            union { u16 us[8]; short8 v; } bu;
            #pragma unroll
            for (int j = 0; j < 8; ++j) bu.us[j] = Xs[(quad*8+j)*XP + bb];
            bfr[fc] = bu.v;
        }
        #pragma unroll
        for (int fr = 0; fr < 4; ++fr)
            #pragma unroll
            for (int fc = 0; fc < 4; ++fc)
                acc[fr][fc] = __builtin_amdgcn_mfma_f32_16x16x32_bf16(
                    afr[fr], bfr[fc], acc[fr][fc], 0, 0, 0);
        __syncthreads();
    }

    // ---- epilogue: out = (acc*vs + vo)*(dc + dt[f]+df[t]) + x
    #pragma unroll
    for (int fr = 0; fr < 4; ++fr) {
        #pragma unroll
        for (int r = 0; r < 4; ++r) {
            int ol = wr*64 + fr*16 + quad*4 + r;
            int o = o0 + ol;
            float vs = vsL[ol], vo = voL[ol], dcv = dcL[ol];
            const size_t orow = xbase + (size_t)o*NSP;
            #pragma unroll
            for (int fc = 0; fc < 4; ++fc) {
                int nl = wc*64 + fc*16 + l16;
                int nn = n0 + nl;
                if (nn < NSP) {
                    size_t gi = orow + nn;
                    out[gi] = (acc[fr][fc][r]*vs + vo)*(dcv + dtfL[nl]) + x[gi];
                }
            }
        }
    }
}

extern "C" void kernel_launch(void* const* d_in, const int* in_sizes, int n_in,
                              void* d_out, int out_size, void* d_ws, size_t ws_size,
                              hipStream_t stream)
{
    const float* x    = (const float*)d_in[0];
    const float* qc_w = (const float*)d_in[1];  const float* qc_bn = (const float*)d_in[2];
    const float* kc_w = (const float*)d_in[3];  const float* kc_bn = (const float*)d_in[4];
    const float* lc_bn= (const float*)d_in[5];
    const float* qf_w = (const float*)d_in[6];  const float* qf_bn = (const float*)d_in[7];
    const float* kf_w = (const float*)d_in[8];  const float* kf_bn = (const float*)d_in[9];
    const float* lf_bn= (const float*)d_in[10];
    const float* qt_w = (const float*)d_in[11]; const float* qt_bn = (const float*)d_in[12];
    const float* kt_w = (const float*)d_in[13]; const float* kt_bn = (const float*)d_in[14];
    const float* lt_bn= (const float*)d_in[15];
    const float* v_w  = (const float*)d_in[16]; const float* v_b   = (const float*)d_in[17];
    const float* v_bn = (const float*)d_in[18];
    float* ws = (float*)d_ws;
    float* out = (float*)d_out;

    prep_kernel<<<7, 256, 0, stream>>>(qc_w,qc_bn,kc_w,kc_bn,lc_bn,
                                       qf_w,qf_bn,kf_w,kf_bn,lf_bn,
                                       qt_w,qt_bn,kt_w,kt_bn,lt_bn,
                                       v_b,v_bn,ws);
    qkv_cf_kernel<<<NB*NF, 256, 0, stream>>>(x, ws);
    t_kernel<<<NB*8, 256, 0, stream>>>(x, ws);
    main_kernel<<<dim3(14, 2, NB), 256, 0, stream>>>(x, v_w, ws, out);
}

// Round 7
// 382.435 us; speedup vs baseline: 1.3498x; 1.0615x over previous
//
#include <hip/hip_runtime.h>

typedef unsigned short u16;
typedef __attribute__((ext_vector_type(8))) short short8;
typedef __attribute__((ext_vector_type(4))) float float4v;

#define EPS 1e-5f
#define NC 256
#define NT 251
#define NF 7
#define NSP 1757   // NF*NT
#define NB 32

// workspace layout (float offsets)
#define OFF_QEC 0
#define OFF_KEC 256
#define OFF_QEF 512
#define OFF_KEF 768
#define OFF_QET 1024
#define OFF_KET 1280
#define OFF_VSC 1536
#define OFF_VOF 1792
#define OFF_CONST 2048   // [0..5]=q/k consts c,f,t  [6]=s_c [7]=s_f [8]=s_t
#define OFF_DC 2064      // 256
#define OFF_DF 2320      // 256 (251 used)
#define OFF_DT 2576      // 16 (7 used)
#define WS_END 2592
// optional fused-t staging (used only if ws_size permits)
#define OFF_QT 2592            // 32*251*7 -> padded 56320
#define OFF_KT (OFF_QT+56320)
#define WS2_END (OFF_KT+56320) // 115232 floats ≈ 461 KB

__device__ __forceinline__ u16 f2b(float f) {   // fp32 -> bf16 RNE
    unsigned int u = __float_as_uint(f);
    return (u16)((u + 0x7FFFu + ((u >> 16) & 1u)) >> 16);
}

// ---------------------------------------------------------------- prep
__global__ __launch_bounds__(256) void prep_kernel(
    const float* qc_w, const float* qc_bn, const float* kc_w, const float* kc_bn, const float* lc_bn,
    const float* qf_w, const float* qf_bn, const float* kf_w, const float* kf_bn, const float* lf_bn,
    const float* qt_w, const float* qt_bn, const float* kt_w, const float* kt_bn, const float* lt_bn,
    const float* v_b, const float* v_bn, float* ws)
{
    int tid = threadIdx.x;
    int blk = blockIdx.x;
    __shared__ float red[256];
    if (blk < 6) {
        const float* w; const float* bn; float* out; int O; float* cdst;
        switch (blk) {
            case 0: w=qc_w; bn=qc_bn; out=ws+OFF_QEC; O=NT; cdst=ws+OFF_CONST+0; break;
            case 1: w=kc_w; bn=kc_bn; out=ws+OFF_KEC; O=NT; cdst=ws+OFF_CONST+1; break;
            case 2: w=qf_w; bn=qf_bn; out=ws+OFF_QEF; O=NC; cdst=ws+OFF_CONST+2; break;
            case 3: w=kf_w; bn=kf_bn; out=ws+OFF_KEF; O=NC; cdst=ws+OFF_CONST+3; break;
            case 4: w=qt_w; bn=qt_bn; out=ws+OFF_QET; O=NC; cdst=ws+OFF_CONST+4; break;
            default: w=kt_w; bn=kt_bn; out=ws+OFF_KET; O=NC; cdst=ws+OFF_CONST+5; break;
        }
        float invO = 1.0f / (float)O;
        if (tid < O) {
            float acc = 0.f;
            for (int o = 0; o < O; ++o) {
                float sc = bn[o] * rsqrtf(bn[3*O+o] + EPS);
                acc = fmaf(sc, w[o*O + tid], acc);
            }
            out[tid] = acc * invO;
        }
        float bs = 0.f;
        for (int o = tid; o < O; o += 256) {
            float sc = bn[o] * rsqrtf(bn[3*O+o] + EPS);
            bs += bn[O+o] - bn[2*O+o]*sc;
        }
        red[tid] = bs; __syncthreads();
        for (int s = 128; s > 0; s >>= 1) { if (tid < s) red[tid] += red[tid+s]; __syncthreads(); }
        if (tid == 0) *cdst = red[0] * invO;
    } else {
        if (tid < NC) {
            float s = v_bn[tid] * rsqrtf(v_bn[3*NC+tid] + EPS);
            ws[OFF_VSC+tid] = s;
            ws[OFF_VOF+tid] = v_bn[NC+tid] - v_bn[2*NC+tid]*s + v_b[tid]*s;
        }
        if (tid == 0) {
            ws[OFF_CONST+6] = lc_bn[0] * rsqrtf(lc_bn[3] + EPS);
            ws[OFF_CONST+7] = lf_bn[0] * rsqrtf(lf_bn[3] + EPS);
            ws[OFF_CONST+8] = lt_bn[0] * rsqrtf(lt_bn[3] + EPS);
        }
        // zero the d accumulators (ws is poisoned 0xAA every call)
        for (int i = tid; i < WS_END - OFF_DC; i += 256) ws[OFF_DC + i] = 0.f;
    }
}

// ------------ qv/kv for all branches + c/f diag softmax, register-accumulated
// block per n=(b,f); no big LDS, full-thread parallel phases.
__global__ __launch_bounds__(256) void qkt_kernel(const float* __restrict__ x,
                                                  float* __restrict__ ws, int fuse_t)
{
    __shared__ float kvc[NC];
    __shared__ float kvf[NT];
    int tid = threadIdx.x;
    int n = blockIdx.x;
    int b = n / NF, f = n % NF;
    const float* xb = x + (size_t)b*NC*NSP + (size_t)f*NT;
    const float* cst = ws + OFF_CONST;

    // ---- phase 1: thread == t, reduce over ch (coalesced lanes along t)
    float qf = 0.f, kf = 0.f, qt = 0.f, kt = 0.f;
    if (tid < NT) {
        const float* xc = xb + tid;
        const float* qeF = ws + OFF_QEF;  const float* keF = ws + OFF_KEF;
        const float* qeT = ws + OFF_QET;  const float* keT = ws + OFF_KET;
        #pragma unroll 8
        for (int ch = 0; ch < NC; ++ch) {
            float xv = xc[(size_t)ch*NSP];
            qf = fmaf(qeF[ch], xv, qf);
            kf = fmaf(keF[ch], xv, kf);
            qt = fmaf(qeT[ch], xv, qt);
            kt = fmaf(keT[ch], xv, kt);
        }
        qf += cst[2]; kf += cst[3];
        qt += cst[4]; kt += cst[5];
        kvf[tid] = kf;
        if (fuse_t) {
            ws[OFF_QT + ((size_t)b*NT + tid)*NF + f] = qt;
            ws[OFF_KT + ((size_t)b*NT + tid)*NF + f] = kt;
        }
    }

    // ---- phase 2: thread == ch, reduce over t (rows stream through L1/L2)
    float qc = 0.f, kc = 0.f;
    {
        const float* xrow = xb + (size_t)tid*NSP;
        const float* qeC = ws + OFF_QEC;  const float* keC = ws + OFF_KEC;
        #pragma unroll 4
        for (int t = 0; t < NT; ++t) {
            float xv = xrow[t];
            qc = fmaf(qeC[t], xv, qc);
            kc = fmaf(keC[t], xv, kc);
        }
        qc += cst[0]; kc += cst[1];
        kvc[tid] = kc;
    }
    __syncthreads();

    // ---- c diag softmax (thread == ch)
    {
        float s = cst[6];
        float qi = s * qc;
        float m = -1e30f;
        for (int j = 0; j < NC; ++j) m = fmaxf(m, qi*kvc[j]);
        float den = 0.f;
        for (int j = 0; j < NC; ++j) den += __expf(qi*kvc[j] - m);
        atomicAdd(&ws[OFF_DC + tid], __expf(qi*kc - m)/den);
    }
    // ---- f diag softmax (thread == t)
    if (tid < NT) {
        float s = cst[7];
        float qi = s * qf;
        float m = -1e30f;
        for (int j = 0; j < NT; ++j) m = fmaxf(m, qi*kvf[j]);
        float den = 0.f;
        for (int j = 0; j < NT; ++j) den += __expf(qi*kvf[j] - m);
        atomicAdd(&ws[OFF_DF + tid], __expf(qi*kf - m)/den);
    }
}

// --------------------- t diag softmax from staged qt/kt (fused path)
__global__ __launch_bounds__(256) void tsm_kernel(float* __restrict__ ws)
{
    __shared__ float dt_acc[NF];
    int tid = threadIdx.x, b = blockIdx.x;
    if (tid < NF) dt_acc[tid] = 0.f;
    __syncthreads();
    if (tid < NT) {
        float s = ws[OFF_CONST+8];
        const float* qp = ws + OFF_QT + ((size_t)b*NT + tid)*NF;
        const float* kp = ws + OFF_KT + ((size_t)b*NT + tid)*NF;
        float q[NF], k[NF];
        #pragma unroll
        for (int i = 0; i < NF; ++i) { q[i] = qp[i]; k[i] = kp[i]; }
        #pragma unroll
        for (int i = 0; i < NF; ++i) {
            float qi = s * q[i];
            float m = -1e30f;
            #pragma unroll
            for (int j = 0; j < NF; ++j) m = fmaxf(m, qi*k[j]);
            float den = 0.f;
            #pragma unroll
            for (int j = 0; j < NF; ++j) den += __expf(qi*k[j] - m);
            atomicAdd(&dt_acc[i], __expf(qi*k[i] - m)/den);
        }
    }
    __syncthreads();
    if (tid < NF) atomicAdd(&ws[OFF_DT + tid], dt_acc[tid]);
}

// --------------------- t-branch fallback (re-reads x; used if ws too small)
__global__ __launch_bounds__(256) void t_kernel(const float* __restrict__ x, float* __restrict__ ws)
{
    __shared__ float qs[32*NF], ks[32*NF], dt_acc[NF];
    int tid = threadIdx.x;
    int b  = blockIdx.x >> 3;
    int t0 = (blockIdx.x & 7) * 32;
    int tl = tid & 31, fr = tid >> 5;
    int t = t0 + tl;
    bool act = (fr < NF) && (t < NT);
    if (tid < NF) dt_acc[tid] = 0.f;

    float aq = 0.f, ak = 0.f;
    const float* qeT = ws + OFF_QET;
    const float* keT = ws + OFF_KET;
    if (act) {
        const float* xr = x + (size_t)b*NC*NSP + fr*NT + t;
        #pragma unroll 8
        for (int ch = 0; ch < NC; ++ch) {
            float xv = xr[(size_t)ch*NSP];
            aq = fmaf(qeT[ch], xv, aq);
            ak = fmaf(keT[ch], xv, ak);
        }
    }
    __syncthreads();
    if (act) {
        qs[tl*NF + fr] = aq + ws[OFF_CONST+4];
        ks[tl*NF + fr] = ak + ws[OFF_CONST+5];
    }
    __syncthreads();
    if (act) {
        float s = ws[OFF_CONST+8];
        float qi = s * qs[tl*NF + fr];
        float m = -1e30f;
        #pragma unroll
        for (int j = 0; j < NF; ++j) m = fmaxf(m, qi*ks[tl*NF + j]);
        float den = 0.f;
        #pragma unroll
        for (int j = 0; j < NF; ++j) den += __expf(qi*ks[tl*NF + j] - m);
        atomicAdd(&dt_acc[fr], __expf(qi*ks[tl*NF + fr] - m)/den);
    }
    __syncthreads();
    if (tid < NF) atomicAdd(&ws[OFF_DT + tid], dt_acc[tid]);
}

// --------------------- main GEMM (v branch) via bf16 MFMA + fused epilogue
#define XP 130
__global__ __launch_bounds__(256) void main_kernel(
    const float* __restrict__ x, const float* __restrict__ vw,
    const float* __restrict__ ws, float* __restrict__ out)
{
    __shared__ u16 Ws[8*512];       // 8 KB
    __shared__ u16 Xs[32*XP];       // 8.3 KB
    __shared__ float vsL[128], voL[128], dcL[128], dtfL[128];

    int tid = threadIdx.x;
    int n0 = blockIdx.x * 128;
    int o0 = blockIdx.y * 128;
    int b  = blockIdx.z;
    const size_t xbase = (size_t)b * NC * NSP;

    if (tid < 128) {
        int o = o0 + tid;
        vsL[tid] = ws[OFF_VSC+o];
        voL[tid] = ws[OFF_VOF+o];
        dcL[tid] = ws[OFF_DC+o];
        int nn = n0 + tid; if (nn > NSP-1) nn = NSP-1;
        int f = nn / NT, t = nn - f*NT;
        dtfL[tid] = ws[OFF_DT+f] + ws[OFF_DF+t];
    }

    int wv = tid >> 6, ln = tid & 63;
    int quad = ln >> 4, l16 = ln & 15;
    int wr = wv >> 1, wc = wv & 1;

    float4v acc[4][4] = {};

    int oo = tid >> 1, half = tid & 1;
    int kk = tid >> 3, ng = tid & 7;

    for (int k0 = 0; k0 < NC; k0 += 32) {
        {
            const float* wr4 = vw + (size_t)(o0+oo)*NC + k0 + half*16;
            union { u16 us[16]; short8 v[2]; } wb;
            #pragma unroll
            for (int c = 0; c < 16; ++c) wb.us[c] = f2b(wr4[c]);
            int frg = oo >> 4, o16 = oo & 15;
            #pragma unroll
            for (int qq = 0; qq < 2; ++qq) {
                int qd = 2*half + qq;
                *(short8*)&Ws[frg*512 + qd*128 + o16*8] = wb.v[qq];
            }
        }
        {
            int nbase = n0 + ng*16;
            const float* xr = x + xbase + (size_t)(k0+kk)*NSP + nbase;
            u16 xb16[16];
            if (nbase + 15 < NSP) {
                #pragma unroll
                for (int c = 0; c < 16; ++c) xb16[c] = f2b(xr[c]);
            } else {
                #pragma unroll
                for (int c = 0; c < 16; ++c)
                    xb16[c] = (nbase + c < NSP) ? f2b(xr[c]) : (u16)0;
            }
            #pragma unroll
            for (int m = 0; m < 8; ++m) {
                unsigned int pk = (unsigned int)xb16[2*m] | ((unsigned int)xb16[2*m+1] << 16);
                *(unsigned int*)&Xs[kk*XP + ng*16 + 2*m] = pk;
            }
        }
        __syncthreads();

        short8 afr[4], bfr[4];
        #pragma unroll
        for (int fr = 0; fr < 4; ++fr)
            afr[fr] = *(short8*)&Ws[(wr*4+fr)*512 + ln*8];
        #pragma unroll
        for (int fc = 0; fc < 4; ++fc) {
            int bb = wc*64 + fc*16 + l16;
            union { u16 us[8]; short8 v; } bu;
            #pragma unroll
            for (int j = 0; j < 8; ++j) bu.us[j] = Xs[(quad*8+j)*XP + bb];
            bfr[fc] = bu.v;
        }
        #pragma unroll
        for (int fr = 0; fr < 4; ++fr)
            #pragma unroll
            for (int fc = 0; fc < 4; ++fc)
                acc[fr][fc] = __builtin_amdgcn_mfma_f32_16x16x32_bf16(
                    afr[fr], bfr[fc], acc[fr][fc], 0, 0, 0);
        __syncthreads();
    }

    #pragma unroll
    for (int fr = 0; fr < 4; ++fr) {
        #pragma unroll
        for (int r = 0; r < 4; ++r) {
            int ol = wr*64 + fr*16 + quad*4 + r;
            int o = o0 + ol;
            float vs = vsL[ol], vo = voL[ol], dcv = dcL[ol];
            const size_t orow = xbase + (size_t)o*NSP;
            #pragma unroll
            for (int fc = 0; fc < 4; ++fc) {
                int nl = wc*64 + fc*16 + l16;
                int nn = n0 + nl;
                if (nn < NSP) {
                    size_t gi = orow + nn;
                    out[gi] = (acc[fr][fc][r]*vs + vo)*(dcv + dtfL[nl]) + x[gi];
                }
            }
        }
    }
}

extern "C" void kernel_launch(void* const* d_in, const int* in_sizes, int n_in,
                              void* d_out, int out_size, void* d_ws, size_t ws_size,
                              hipStream_t stream)
{
    const float* x    = (const float*)d_in[0];
    const float* qc_w = (const float*)d_in[1];  const float* qc_bn = (const float*)d_in[2];
    const float* kc_w = (const float*)d_in[3];  const float* kc_bn = (const float*)d_in[4];
    const float* lc_bn= (const float*)d_in[5];
    const float* qf_w = (const float*)d_in[6];  const float* qf_bn = (const float*)d_in[7];
    const float* kf_w = (const float*)d_in[8];  const float* kf_bn = (const float*)d_in[9];
    const float* lf_bn= (const float*)d_in[10];
    const float* qt_w = (const float*)d_in[11]; const float* qt_bn = (const float*)d_in[12];
    const float* kt_w = (const float*)d_in[13]; const float* kt_bn = (const float*)d_in[14];
    const float* lt_bn= (const float*)d_in[15];
    const float* v_w  = (const float*)d_in[16]; const float* v_b   = (const float*)d_in[17];
    const float* v_bn = (const float*)d_in[18];
    float* ws = (float*)d_ws;
    float* out = (float*)d_out;

    int fuse_t = (ws_size >= (size_t)WS2_END * sizeof(float)) ? 1 : 0;

    prep_kernel<<<7, 256, 0, stream>>>(qc_w,qc_bn,kc_w,kc_bn,lc_bn,
                                       qf_w,qf_bn,kf_w,kf_bn,lf_bn,
                                       qt_w,qt_bn,kt_w,kt_bn,lt_bn,
                                       v_b,v_bn,ws);
    qkt_kernel<<<NB*NF, 256, 0, stream>>>(x, ws, fuse_t);
    if (fuse_t) tsm_kernel<<<NB, 256, 0, stream>>>(ws);
    else        t_kernel<<<NB*8, 256, 0, stream>>>(x, ws);
    main_kernel<<<dim3(14, 2, NB), 256, 0, stream>>>(x, v_w, ws, out);
}